// Round 1
// baseline (2330.531 us; speedup 1.0000x reference)
//
#include <hip/hip_runtime.h>

// PixelVectorQuantizer: z [16,256,64,64] f32, codebook [1024,256] f32
// outputs: zq [16,256,64,64] f32, indices [16,1,64,64] (written as f32 values)
//
// Strategy: stage1 = fp32 register-blocked distance + running best/second;
// pixels with top-2 gap < MARGIN are flagged and re-resolved exactly in f64
// (stage2, one wave per flagged pixel). zq = exact gather of fp32 codebook.

#define HWSZ 4096   // 64*64
#define CDIM 256
#define KCODES 1024
#define NPIX 65536
#define ZQ_ELEMS (16 * 256 * 4096)  // 16777216
#define MARGIN 0.125f

// ws layout:
// [0, 8192)      double cbnorm64[1024]
// [8192, 12288)  float  cbnorm32[1024]
// [12288, 12292) int    count
// [12544, ...)   int    flags[cap]

__global__ void cbnorm_kernel(const float* __restrict__ cb,
                              double* __restrict__ cbn64,
                              float* __restrict__ cbn32) {
  int k = blockIdx.x * blockDim.x + threadIdx.x;
  if (k >= KCODES) return;
  const float* r = cb + k * CDIM;
  double s = 0.0;
  for (int c = 0; c < CDIM; ++c) {
    double v = (double)r[c];
    s = fma(v, v, s);
  }
  cbn64[k] = s;
  cbn32[k] = (float)s;
}

// Stage 1: block = 256 threads, 128 pixels/block, each pixel split across 2
// threads (k-halves 0..511 / 512..1023). grid = 512 blocks.
__launch_bounds__(256)
__global__ void vq_stage1(const float* __restrict__ z,
                          const float* __restrict__ cb,
                          const float* __restrict__ cbn32,
                          float* __restrict__ out_zq,
                          float* __restrict__ out_idx,
                          int* __restrict__ cnt,
                          int* __restrict__ flags,
                          int flag_cap) {
  const int t = threadIdx.x;
  const int px = t & 127;
  const int kh = t >> 7;  // 0 or 1
  const int p = blockIdx.x * 128 + px;
  const int b = p >> 12;
  const int hw = p & (HWSZ - 1);
  const float* zb = z + (size_t)b * (CDIM * HWSZ) + hw;

  float m1 = 1e30f, m2 = 1e30f;
  int i1 = 0;

  const int k0 = kh * 512;
  for (int kc = 0; kc < 512; kc += 32) {
    // kbase is wave-uniform (kh constant within a wave); help scalarization
    const int kbase = __builtin_amdgcn_readfirstlane(k0 + kc);
    float acc[32];
#pragma unroll
    for (int k = 0; k < 32; ++k) acc[k] = 0.f;

    for (int cc = 0; cc < CDIM; cc += 8) {
      float zv[8];
#pragma unroll
      for (int j = 0; j < 8; ++j) zv[j] = zb[(cc + j) * HWSZ];
#pragma unroll
      for (int k = 0; k < 32; ++k) {
        const float* cr = cb + (kbase + k) * CDIM + cc;
        float a = acc[k];
#pragma unroll
        for (int j = 0; j < 8; ++j) a = fmaf(zv[j], cr[j], a);
        acc[k] = a;
      }
    }

#pragma unroll
    for (int k = 0; k < 32; ++k) {
      // m_k = ||c_k||^2 - 2 z.c_k  (||z||^2 irrelevant for argmin)
      float m = fmaf(-2.f, acc[k], cbn32[kbase + k]);
      int ki = kbase + k;
      if (m < m1) { m2 = m1; m1 = m; i1 = ki; }
      else if (m < m2) { m2 = m; }
    }
  }

  __shared__ float sm1[256], sm2[256];
  __shared__ int si1[256];
  __shared__ int sbest[128];
  sm1[t] = m1; sm2[t] = m2; si1[t] = i1;
  __syncthreads();

  if (kh == 0) {
    const float am1 = m1, am2 = m2; const int ai = i1;
    const float bm1 = sm1[t + 128], bm2 = sm2[t + 128];
    const int bi = si1[t + 128];
    float fm1, fm2; int fi;
    if (bm1 < am1) { fm1 = bm1; fi = bi; fm2 = fminf(am1, bm2); }
    else           { fm1 = am1; fi = ai; fm2 = fminf(bm1, am2); }
    sbest[px] = fi;
    out_idx[p] = (float)fi;
    if (fm2 - fm1 < MARGIN) {
      int pos = atomicAdd(cnt, 1);
      if (pos < flag_cap) flags[pos] = p;
    }
  }
  __syncthreads();

  // zq gather-write: this thread writes channels [kh*128, kh*128+128)
  const int bi = sbest[px];
  const float* crow = cb + (size_t)bi * CDIM + kh * 128;
  float* ob = out_zq + (size_t)b * (CDIM * HWSZ) + hw + (size_t)(kh * 128) * HWSZ;
#pragma unroll 4
  for (int c = 0; c < 128; c += 4) {
    float4 v = *reinterpret_cast<const float4*>(crow + c);
    ob[(c + 0) * HWSZ] = v.x;
    ob[(c + 1) * HWSZ] = v.y;
    ob[(c + 2) * HWSZ] = v.z;
    ob[(c + 3) * HWSZ] = v.w;
  }
}

// Stage 2: exact f64 re-resolution of flagged pixels. One wave per pixel;
// lane l handles codes [16l, 16l+16).
__launch_bounds__(256)
__global__ void vq_stage2(const float* __restrict__ z,
                          const float* __restrict__ cb,
                          const double* __restrict__ cbn64,
                          float* __restrict__ out_zq,
                          float* __restrict__ out_idx,
                          const int* __restrict__ cnt,
                          const int* __restrict__ flags,
                          int flag_cap) {
  const int lane = threadIdx.x & 63;
  const int wid = (blockIdx.x * blockDim.x + threadIdx.x) >> 6;
  const int nw = (gridDim.x * blockDim.x) >> 6;
  int n = *cnt;
  if (n > flag_cap) n = flag_cap;

  for (int i = wid; i < n; i += nw) {
    const int p = flags[i];
    const int b = p >> 12;
    const int hw = p & (HWSZ - 1);
    const float* zb = z + (size_t)b * (CDIM * HWSZ) + hw;
    const int k0 = lane * 16;

    double acc[16];
#pragma unroll
    for (int k = 0; k < 16; ++k) acc[k] = 0.0;

    for (int cc = 0; cc < CDIM; cc += 4) {
      float zv[4];
#pragma unroll
      for (int j = 0; j < 4; ++j) zv[j] = zb[(cc + j) * HWSZ];
#pragma unroll
      for (int k = 0; k < 16; ++k) {
        float4 cv = *reinterpret_cast<const float4*>(cb + (size_t)(k0 + k) * CDIM + cc);
        acc[k] = fma((double)zv[0], (double)cv.x, acc[k]);
        acc[k] = fma((double)zv[1], (double)cv.y, acc[k]);
        acc[k] = fma((double)zv[2], (double)cv.z, acc[k]);
        acc[k] = fma((double)zv[3], (double)cv.w, acc[k]);
      }
    }

    double m1 = 1e300;
    int i1 = 0;
#pragma unroll
    for (int k = 0; k < 16; ++k) {
      double m = fma(-2.0, acc[k], cbn64[k0 + k]);
      if (m < m1) { m1 = m; i1 = k0 + k; }  // ascending k: first-min wins
    }
    // wave-wide min reduce with smallest-index tie-break (matches np.argmin)
    for (int off = 32; off; off >>= 1) {
      double om = __shfl_xor(m1, off, 64);
      int oi = __shfl_xor(i1, off, 64);
      if (om < m1 || (om == m1 && oi < i1)) { m1 = om; i1 = oi; }
    }

    if (lane == 0) out_idx[p] = (float)i1;
    const float* crow = cb + (size_t)i1 * CDIM;
    float* ob = out_zq + (size_t)b * (CDIM * HWSZ) + hw;
    for (int c = lane; c < CDIM; c += 64) ob[(size_t)c * HWSZ] = crow[c];
  }
}

extern "C" void kernel_launch(void* const* d_in, const int* in_sizes, int n_in,
                              void* d_out, int out_size, void* d_ws, size_t ws_size,
                              hipStream_t stream) {
  const float* z = (const float*)d_in[0];
  const float* cb = (const float*)d_in[1];
  float* out = (float*)d_out;
  float* out_zq = out;
  float* out_idx = out + ZQ_ELEMS;

  char* ws = (char*)d_ws;
  double* cbn64 = (double*)ws;
  float* cbn32 = (float*)(ws + 8192);
  int* cnt = (int*)(ws + 12288);
  int* flags = (int*)(ws + 12544);
  long long avail = (long long)ws_size - 12544;
  int flag_cap = avail > 0 ? (int)((avail / 4 < NPIX) ? avail / 4 : NPIX) : 0;

  hipMemsetAsync(cnt, 0, 4, stream);
  cbnorm_kernel<<<4, 256, 0, stream>>>(cb, cbn64, cbn32);
  vq_stage1<<<512, 256, 0, stream>>>(z, cb, cbn32, out_zq, out_idx, cnt, flags, flag_cap);
  vq_stage2<<<128, 256, 0, stream>>>(z, cb, cbn64, out_zq, out_idx, cnt, flags, flag_cap);
}

// Round 2
// 946.862 us; speedup vs baseline: 2.4613x; 2.4613x over previous
//
#include <hip/hip_runtime.h>

// PixelVectorQuantizer: z [16,256,64,64] f32, codebook [1024,256] f32
// outputs: zq (f32) + indices (as f32 values), concatenated in d_out.
//
// stage1: bf16 MFMA distance GEMM (16x16x32), per-lane top-2 tracking,
//         flag pixels with top-2 gap < MARGIN.
// stage2: exact f64 re-resolution of flagged pixels (argmin stays exact).

#define HWSZ 4096
#define CDIM 256
#define KCODES 1024
#define NPIX 65536
#define ZQ_ELEMS (16 * 256 * 4096)
#define MARGIN 0.75f

// ws layout
#define WS_CBSWZ 0          // 1024*256 bf16, chunked+swizzled: 524288 B
#define WS_CBN64 524288     // double[1024]
#define WS_CBN32 532480     // float[1024]
#define WS_CNT   536576     // int
#define WS_FLAGS 536832     // int[flag_cap]

typedef __attribute__((ext_vector_type(8))) short bf16x8;
typedef __attribute__((ext_vector_type(4))) float f32x4;
typedef __attribute__((ext_vector_type(4))) unsigned short us4;

#define MFMA16(a, b, c) __builtin_amdgcn_mfma_f32_16x16x32_bf16(a, b, c, 0, 0, 0)

__device__ __forceinline__ unsigned short f2bf(float f) {
  unsigned u = __float_as_uint(f);
  unsigned r = u + 0x7FFFu + ((u >> 16) & 1u);   // RNE
  return (unsigned short)(r >> 16);
}

__device__ __forceinline__ void gload_lds16(const void* g, void* l) {
  __builtin_amdgcn_global_load_lds(
      (const __attribute__((address_space(1))) unsigned int*)g,
      (__attribute__((address_space(3))) unsigned int*)l, 16, 0, 0);
}

__global__ void prep_norms(const float* __restrict__ cb,
                           double* __restrict__ cbn64,
                           float* __restrict__ cbn32) {
  int k = blockIdx.x * blockDim.x + threadIdx.x;
  if (k >= KCODES) return;
  const float* r = cb + (size_t)k * CDIM;
  double s = 0.0;
  for (int c = 0; c < CDIM; ++c) {
    double v = (double)r[c];
    s = fma(v, v, s);
  }
  cbn64[k] = s;
  cbn32[k] = (float)s;
}

// cbswz: 16 chunks of 64 codes; within a chunk, code r at bytes
// [r*512, r*512+512) with byte ^= ((r&7)<<4) (bank-conflict swizzle).
__global__ void prep_cbswz(const float* __restrict__ cb,
                           unsigned short* __restrict__ cbswz) {
  int g = blockIdx.x * blockDim.x + threadIdx.x;  // 65536 threads
  int code = g >> 6;
  int c4 = (g & 63) * 4;
  float4 v = *(const float4*)(cb + (size_t)code * CDIM + c4);
  us4 hv;
  hv.x = f2bf(v.x); hv.y = f2bf(v.y); hv.z = f2bf(v.z); hv.w = f2bf(v.w);
  unsigned r = (unsigned)(code & 63);
  unsigned off = ((r << 9) + (unsigned)(c4 << 1)) ^ ((r & 7) << 4);
  *(us4*)((char*)cbswz + (size_t)(code >> 6) * 32768 + off) = hv;
}

// Stage 1: 512 blocks x 256 thr. Block = 128 px (4 waves x 32 px).
// LDS (64 KB dynamic): region reused: A tile [128px][256ch] bf16 swizzled,
// then 2x 32 KB B double-buffers, then sbest[128].
__launch_bounds__(256, 2)
__global__ void vq_stage1(const float* __restrict__ z,
                          const float* __restrict__ cb,
                          const unsigned short* __restrict__ cbswz,
                          const float* __restrict__ cbn32,
                          float* __restrict__ out_zq,
                          float* __restrict__ out_idx,
                          int* __restrict__ cnt,
                          int* __restrict__ flags,
                          int flag_cap) {
  extern __shared__ char smem[];
  const int t = threadIdx.x;
  const int w = t >> 6;
  const int lane = t & 63;
  const int p0 = blockIdx.x * 128;
  const int b = p0 >> 12;
  const int hw0 = p0 & (HWSZ - 1);
  const float* zb = z + (size_t)b * (CDIM * HWSZ) + hw0;

  // ---- stage A: z tile -> LDS bf16, [px][ch], swizzled ----
  {
    const int px = t & 127;
    const int chh = t >> 7;  // 0/1
    const unsigned rowbase = ((unsigned)px << 9);
    const unsigned sw = ((unsigned)(px & 7)) << 4;
#pragma unroll 4
    for (int i = 0; i < 128; ++i) {
      int ch = chh + i * 2;
      float v = zb[(size_t)ch * HWSZ + px];
      unsigned off = (rowbase + ((unsigned)ch << 1)) ^ sw;
      *(unsigned short*)(smem + off) = f2bf(v);
    }
  }
  __syncthreads();

  // ---- A frags (32 px x 256 ch per wave) -> registers ----
  bf16x8 af[2][8];
#pragma unroll
  for (int T = 0; T < 2; ++T) {
#pragma unroll
    for (int kk = 0; kk < 8; ++kk) {
      int row = w * 32 + T * 16 + (lane & 15);
      unsigned off = (((unsigned)row << 9) + ((unsigned)kk << 6) +
                      (((unsigned)(lane >> 4)) << 4)) ^
                     (((unsigned)(row & 7)) << 4);
      af[T][kk] = *(const bf16x8*)(smem + off);
    }
  }
  __syncthreads();

  // ---- prologue: chunk 0 -> buf 0 ----
  {
    const char* gsrc = (const char*)cbswz + w * 8192;
    char* ldst = smem + w * 8192;
#pragma unroll
    for (int j = 0; j < 8; ++j)
      gload_lds16(gsrc + j * 1024 + lane * 16, ldst + j * 1024);
  }
  __syncthreads();

  float m1[2][4], m2[2][4];
  int bi[2][4];
#pragma unroll
  for (int T = 0; T < 2; ++T)
#pragma unroll
    for (int i2 = 0; i2 < 4; ++i2) {
      m1[T][i2] = 1e30f; m2[T][i2] = 1e30f; bi[T][i2] = 0;
    }

  const unsigned rsw = ((unsigned)(lane & 7)) << 4;     // (r&7)<<4
  const unsigned kl16 = ((unsigned)(lane >> 4)) << 4;

  for (int c = 0; c < 16; ++c) {
    const char* rbuf = smem + (c & 1) * 32768;
    if (c < 15) {
      const char* gsrc = (const char*)cbswz + (c + 1) * 32768 + w * 8192;
      char* ldst = smem + ((c + 1) & 1) * 32768 + w * 8192;
#pragma unroll
      for (int j = 0; j < 8; ++j)
        gload_lds16(gsrc + j * 1024 + lane * 16, ldst + j * 1024);
    }
#pragma unroll
    for (int cs = 0; cs < 4; ++cs) {
      const int r = cs * 16 + (lane & 15);
      const unsigned base = ((unsigned)r << 9) + kl16;
      f32x4 acc0 = {0.f, 0.f, 0.f, 0.f};
      f32x4 acc1 = {0.f, 0.f, 0.f, 0.f};
#pragma unroll
      for (int kk = 0; kk < 8; ++kk) {
        bf16x8 bf = *(const bf16x8*)(rbuf + ((base + ((unsigned)kk << 6)) ^ rsw));
        acc0 = MFMA16(af[0][kk], bf, acc0);
        acc1 = MFMA16(af[1][kk], bf, acc1);
      }
      const int code = c * 64 + cs * 16 + (lane & 15);
      const float cn = cbn32[code];
#pragma unroll
      for (int i2 = 0; i2 < 4; ++i2) {
        {
          float m = fmaf(-2.f, acc0[i2], cn);
          float o = m1[0][i2];
          bool lt = m < o;
          m2[0][i2] = fminf(m2[0][i2], lt ? o : m);
          m1[0][i2] = lt ? m : o;
          bi[0][i2] = lt ? code : bi[0][i2];
        }
        {
          float m = fmaf(-2.f, acc1[i2], cn);
          float o = m1[1][i2];
          bool lt = m < o;
          m2[1][i2] = fminf(m2[1][i2], lt ? o : m);
          m1[1][i2] = lt ? m : o;
          bi[1][i2] = lt ? code : bi[1][i2];
        }
      }
    }
    __syncthreads();
  }

  // ---- cross-lane top-2 merge over the 16-column group ----
#pragma unroll
  for (int mask = 1; mask <= 8; mask <<= 1) {
#pragma unroll
    for (int T = 0; T < 2; ++T)
#pragma unroll
      for (int i2 = 0; i2 < 4; ++i2) {
        float o1 = __shfl_xor(m1[T][i2], mask, 64);
        float o2 = __shfl_xor(m2[T][i2], mask, 64);
        int oi = __shfl_xor(bi[T][i2], mask, 64);
        float n2 = fminf(fminf(m2[T][i2], o2), fmaxf(m1[T][i2], o1));
        bool lt = o1 < m1[T][i2];
        bi[T][i2] = lt ? oi : bi[T][i2];
        m1[T][i2] = fminf(m1[T][i2], o1);
        m2[T][i2] = n2;
      }
  }

  int* sbest = (int*)smem;  // B buffers dead now
  if ((lane & 15) == 0) {
#pragma unroll
    for (int T = 0; T < 2; ++T)
#pragma unroll
      for (int i2 = 0; i2 < 4; ++i2) {
        int row = w * 32 + T * 16 + (lane >> 4) * 4 + i2;
        int p = p0 + row;
        sbest[row] = bi[T][i2];
        out_idx[p] = (float)bi[T][i2];
        if (m2[T][i2] - m1[T][i2] < MARGIN) {
          int pos = atomicAdd(cnt, 1);
          if (pos < flag_cap) flags[pos] = p;
        }
      }
  }
  __syncthreads();

  // ---- zq gather: coalesced over px, cb reads hit L2 ----
  {
    const int px = t & 127;
    const int best = sbest[px];
    const int ch0g = (t >> 7) * 128;
    const float* crow = cb + (size_t)best * CDIM + ch0g;
    float* ob = out_zq + (size_t)b * (CDIM * HWSZ) + (size_t)ch0g * HWSZ + hw0 + px;
#pragma unroll 4
    for (int c2 = 0; c2 < 128; c2 += 4) {
      float4 v = *(const float4*)(crow + c2);
      ob[(size_t)(c2 + 0) * HWSZ] = v.x;
      ob[(size_t)(c2 + 1) * HWSZ] = v.y;
      ob[(size_t)(c2 + 2) * HWSZ] = v.z;
      ob[(size_t)(c2 + 3) * HWSZ] = v.w;
    }
  }
}

// Stage 2: exact f64 re-resolution of flagged pixels. One wave per pixel.
__launch_bounds__(256)
__global__ void vq_stage2(const float* __restrict__ z,
                          const float* __restrict__ cb,
                          const double* __restrict__ cbn64,
                          float* __restrict__ out_zq,
                          float* __restrict__ out_idx,
                          const int* __restrict__ cnt,
                          const int* __restrict__ flags,
                          int flag_cap) {
  const int lane = threadIdx.x & 63;
  const int wid = (blockIdx.x * blockDim.x + threadIdx.x) >> 6;
  const int nw = (gridDim.x * blockDim.x) >> 6;
  int n = *cnt;
  if (n > flag_cap) n = flag_cap;

  for (int i = wid; i < n; i += nw) {
    const int p = flags[i];
    const int b = p >> 12;
    const int hw = p & (HWSZ - 1);
    const float* zb = z + (size_t)b * (CDIM * HWSZ) + hw;
    const int k0 = lane * 16;

    double acc[16];
#pragma unroll
    for (int k = 0; k < 16; ++k) acc[k] = 0.0;

    for (int cc = 0; cc < CDIM; cc += 4) {
      float zv[4];
#pragma unroll
      for (int j = 0; j < 4; ++j) zv[j] = zb[(size_t)(cc + j) * HWSZ];
#pragma unroll
      for (int k = 0; k < 16; ++k) {
        float4 cv = *reinterpret_cast<const float4*>(cb + (size_t)(k0 + k) * CDIM + cc);
        acc[k] = fma((double)zv[0], (double)cv.x, acc[k]);
        acc[k] = fma((double)zv[1], (double)cv.y, acc[k]);
        acc[k] = fma((double)zv[2], (double)cv.z, acc[k]);
        acc[k] = fma((double)zv[3], (double)cv.w, acc[k]);
      }
    }

    double m1 = 1e300;
    int i1 = 0;
#pragma unroll
    for (int k = 0; k < 16; ++k) {
      double m = fma(-2.0, acc[k], cbn64[k0 + k]);
      if (m < m1) { m1 = m; i1 = k0 + k; }
    }
    for (int off = 32; off; off >>= 1) {
      double om = __shfl_xor(m1, off, 64);
      int oi = __shfl_xor(i1, off, 64);
      if (om < m1 || (om == m1 && oi < i1)) { m1 = om; i1 = oi; }
    }

    if (lane == 0) out_idx[p] = (float)i1;
    const float* crow = cb + (size_t)i1 * CDIM;
    float* ob = out_zq + (size_t)b * (CDIM * HWSZ) + hw;
    for (int c = lane; c < CDIM; c += 64) ob[(size_t)c * HWSZ] = crow[c];
  }
}

extern "C" void kernel_launch(void* const* d_in, const int* in_sizes, int n_in,
                              void* d_out, int out_size, void* d_ws, size_t ws_size,
                              hipStream_t stream) {
  const float* z = (const float*)d_in[0];
  const float* cb = (const float*)d_in[1];
  float* out = (float*)d_out;
  float* out_zq = out;
  float* out_idx = out + ZQ_ELEMS;

  char* ws = (char*)d_ws;
  unsigned short* cbswz = (unsigned short*)(ws + WS_CBSWZ);
  double* cbn64 = (double*)(ws + WS_CBN64);
  float* cbn32 = (float*)(ws + WS_CBN32);
  int* cnt = (int*)(ws + WS_CNT);
  int* flags = (int*)(ws + WS_FLAGS);
  long long avail = (long long)ws_size - WS_FLAGS;
  int flag_cap = avail > 0 ? (int)((avail / 4 < NPIX) ? avail / 4 : NPIX) : 0;

  hipMemsetAsync(cnt, 0, 4, stream);
  prep_norms<<<4, 256, 0, stream>>>(cb, cbn64, cbn32);
  prep_cbswz<<<256, 256, 0, stream>>>(cb, cbswz);
  vq_stage1<<<512, 256, 65536, stream>>>(z, cb, cbswz, cbn32, out_zq, out_idx,
                                         cnt, flags, flag_cap);
  vq_stage2<<<256, 256, 0, stream>>>(z, cb, cbn64, out_zq, out_idx,
                                     cnt, flags, flag_cap);
}

// Round 3
// 224.789 us; speedup vs baseline: 10.3676x; 4.2122x over previous
//
#include <hip/hip_runtime.h>

// PixelVectorQuantizer: z [16,256,64,64] f32, codebook [1024,256] f32
// outputs: zq (f32) + indices (as f32 values), concatenated in d_out.
//
// stage1:   bf16 MFMA distance GEMM (16x16x32), per-lane TOP-3 tracking.
//           unflagged -> done; gap2 < MARGIN -> listA (3 candidates);
//           gap3 < MARGIN -> listB (full rescan).
// stage2a:  exact f64 distance for the 3 candidates (coalesced, wave/pixel).
// stage2b:  exact f64 full scan for triple-near-ties (coalesced, block/pixel).

#define HWSZ 4096
#define CDIM 256
#define KCODES 1024
#define NPIX 65536
#define ZQ_ELEMS (16 * 256 * 4096)
#define MARGIN 0.75f

// ws layout (fixed part)
#define WS_CBSWZ 0          // 1024*256 bf16 chunked+swizzled: 524288 B
#define WS_CBN64 524288     // double[1024]
#define WS_CBN32 532480     // float[1024]
#define WS_CNT   536576     // int cntA, int cntB
#define WS_LISTS 536592     // listA (8B/entry) then listB (4B/entry)

typedef __attribute__((ext_vector_type(8))) short bf16x8;
typedef __attribute__((ext_vector_type(4))) float f32x4;
typedef __attribute__((ext_vector_type(4))) unsigned short us4;

#define MFMA16(a, b, c) __builtin_amdgcn_mfma_f32_16x16x32_bf16(a, b, c, 0, 0, 0)

__device__ __forceinline__ unsigned short f2bf(float f) {
  unsigned u = __float_as_uint(f);
  unsigned r = u + 0x7FFFu + ((u >> 16) & 1u);   // RNE
  return (unsigned short)(r >> 16);
}

__device__ __forceinline__ void gload_lds16(const void* g, void* l) {
  __builtin_amdgcn_global_load_lds(
      (const __attribute__((address_space(1))) unsigned int*)g,
      (__attribute__((address_space(3))) unsigned int*)l, 16, 0, 0);
}

__global__ void prep_norms(const float* __restrict__ cb,
                           double* __restrict__ cbn64,
                           float* __restrict__ cbn32) {
  int k = blockIdx.x * blockDim.x + threadIdx.x;
  if (k >= KCODES) return;
  const float* r = cb + (size_t)k * CDIM;
  double s = 0.0;
  for (int c = 0; c < CDIM; ++c) {
    double v = (double)r[c];
    s = fma(v, v, s);
  }
  cbn64[k] = s;
  cbn32[k] = (float)s;
}

// cbswz: 16 chunks of 64 codes; code r at bytes [r*512, r*512+512),
// byte ^= ((r&7)<<4) (bank-conflict swizzle, inverse-applied at source).
__global__ void prep_cbswz(const float* __restrict__ cb,
                           unsigned short* __restrict__ cbswz) {
  int g = blockIdx.x * blockDim.x + threadIdx.x;  // 65536 threads
  int code = g >> 6;
  int c4 = (g & 63) * 4;
  float4 v = *(const float4*)(cb + (size_t)code * CDIM + c4);
  us4 hv;
  hv.x = f2bf(v.x); hv.y = f2bf(v.y); hv.z = f2bf(v.z); hv.w = f2bf(v.w);
  unsigned r = (unsigned)(code & 63);
  unsigned off = ((r << 9) + (unsigned)(c4 << 1)) ^ ((r & 7) << 4);
  *(us4*)((char*)cbswz + (size_t)(code >> 6) * 32768 + off) = hv;
}

// Stage 1: 512 blocks x 256 thr, 128 px/block (4 waves x 32 px).
__launch_bounds__(256, 2)
__global__ void vq_stage1(const float* __restrict__ z,
                          const float* __restrict__ cb,
                          const unsigned short* __restrict__ cbswz,
                          const float* __restrict__ cbn32,
                          float* __restrict__ out_zq,
                          float* __restrict__ out_idx,
                          int* __restrict__ cnt,      // [cntA, cntB]
                          int* __restrict__ listA, int capA,
                          int* __restrict__ listB, int capB) {
  extern __shared__ char smem[];
  const int t = threadIdx.x;
  const int w = t >> 6;
  const int lane = t & 63;
  const int p0 = blockIdx.x * 128;
  const int b = p0 >> 12;
  const int hw0 = p0 & (HWSZ - 1);
  const float* zb = z + (size_t)b * (CDIM * HWSZ) + hw0;

  // ---- z tile -> LDS bf16, [px][ch], swizzled ----
  {
    const int px = t & 127;
    const int chh = t >> 7;  // 0/1
    const unsigned rowbase = ((unsigned)px << 9);
    const unsigned sw = ((unsigned)(px & 7)) << 4;
#pragma unroll 4
    for (int i = 0; i < 128; ++i) {
      int ch = chh + i * 2;
      float v = zb[(size_t)ch * HWSZ + px];
      unsigned off = (rowbase + ((unsigned)ch << 1)) ^ sw;
      *(unsigned short*)(smem + off) = f2bf(v);
    }
  }
  __syncthreads();

  // ---- A frags (32 px x 256 ch per wave) -> registers ----
  bf16x8 af[2][8];
#pragma unroll
  for (int T = 0; T < 2; ++T) {
#pragma unroll
    for (int kk = 0; kk < 8; ++kk) {
      int row = w * 32 + T * 16 + (lane & 15);
      unsigned off = (((unsigned)row << 9) + ((unsigned)kk << 6) +
                      (((unsigned)(lane >> 4)) << 4)) ^
                     (((unsigned)(row & 7)) << 4);
      af[T][kk] = *(const bf16x8*)(smem + off);
    }
  }
  __syncthreads();

  // ---- prologue: chunk 0 -> buf 0 ----
  {
    const char* gsrc = (const char*)cbswz + w * 8192;
    char* ldst = smem + w * 8192;
#pragma unroll
    for (int j = 0; j < 8; ++j)
      gload_lds16(gsrc + j * 1024 + lane * 16, ldst + j * 1024);
  }
  __syncthreads();

  float m1[2][4], m2[2][4], m3[2][4];
  int i1[2][4], i2a[2][4], i3a[2][4];
#pragma unroll
  for (int T = 0; T < 2; ++T)
#pragma unroll
    for (int q = 0; q < 4; ++q) {
      m1[T][q] = 1e30f; m2[T][q] = 1e30f; m3[T][q] = 1e30f;
      i1[T][q] = 0; i2a[T][q] = 0; i3a[T][q] = 0;
    }

  const unsigned rsw = ((unsigned)(lane & 7)) << 4;
  const unsigned kl16 = ((unsigned)(lane >> 4)) << 4;

  for (int c = 0; c < 16; ++c) {
    const char* rbuf = smem + (c & 1) * 32768;
    if (c < 15) {
      const char* gsrc = (const char*)cbswz + (c + 1) * 32768 + w * 8192;
      char* ldst = smem + ((c + 1) & 1) * 32768 + w * 8192;
#pragma unroll
      for (int j = 0; j < 8; ++j)
        gload_lds16(gsrc + j * 1024 + lane * 16, ldst + j * 1024);
    }
#pragma unroll
    for (int cs = 0; cs < 4; ++cs) {
      const int r = cs * 16 + (lane & 15);
      const unsigned base = ((unsigned)r << 9) + kl16;
      f32x4 acc0 = {0.f, 0.f, 0.f, 0.f};
      f32x4 acc1 = {0.f, 0.f, 0.f, 0.f};
#pragma unroll
      for (int kk = 0; kk < 8; ++kk) {
        bf16x8 bf = *(const bf16x8*)(rbuf + ((base + ((unsigned)kk << 6)) ^ rsw));
        acc0 = MFMA16(af[0][kk], bf, acc0);
        acc1 = MFMA16(af[1][kk], bf, acc1);
      }
      const int code = c * 64 + cs * 16 + (lane & 15);
      const float cn = cbn32[code];
#pragma unroll
      for (int T = 0; T < 2; ++T)
#pragma unroll
        for (int q = 0; q < 4; ++q) {
          float av = (T == 0) ? acc0[q] : acc1[q];
          float m = fmaf(-2.f, av, cn);
          bool lt1 = m < m1[T][q];
          bool lt2 = m < m2[T][q];
          bool lt3 = m < m3[T][q];
          m3[T][q] = lt2 ? m2[T][q] : (lt3 ? m : m3[T][q]);
          i3a[T][q] = lt2 ? i2a[T][q] : (lt3 ? code : i3a[T][q]);
          m2[T][q] = lt1 ? m1[T][q] : (lt2 ? m : m2[T][q]);
          i2a[T][q] = lt1 ? i1[T][q] : (lt2 ? code : i2a[T][q]);
          m1[T][q] = lt1 ? m : m1[T][q];
          i1[T][q] = lt1 ? code : i1[T][q];
        }
    }
    __syncthreads();
  }

  // ---- cross-lane top-3 merge over the 16-column group ----
#pragma unroll
  for (int mask = 1; mask <= 8; mask <<= 1) {
#pragma unroll
    for (int T = 0; T < 2; ++T)
#pragma unroll
      for (int q = 0; q < 4; ++q) {
        float om[3];
        int oi[3];
        om[0] = __shfl_xor(m1[T][q], mask, 64);
        om[1] = __shfl_xor(m2[T][q], mask, 64);
        om[2] = __shfl_xor(m3[T][q], mask, 64);
        oi[0] = __shfl_xor(i1[T][q], mask, 64);
        oi[1] = __shfl_xor(i2a[T][q], mask, 64);
        oi[2] = __shfl_xor(i3a[T][q], mask, 64);
#pragma unroll
        for (int s = 0; s < 3; ++s) {
          // insert (om[s], oi[s]) into sorted triple
          bool l3 = om[s] < m3[T][q];
          float tm = l3 ? om[s] : m3[T][q];
          int ti = l3 ? oi[s] : i3a[T][q];
          bool l2 = tm < m2[T][q];
          m3[T][q] = l2 ? m2[T][q] : tm;
          i3a[T][q] = l2 ? i2a[T][q] : ti;
          float nm2 = l2 ? tm : m2[T][q];
          int ni2 = l2 ? ti : i2a[T][q];
          bool l1 = nm2 < m1[T][q];
          m2[T][q] = l1 ? m1[T][q] : nm2;
          i2a[T][q] = l1 ? i1[T][q] : ni2;
          m1[T][q] = l1 ? nm2 : m1[T][q];
          i1[T][q] = l1 ? ni2 : i1[T][q];
        }
      }
  }

  int* sbest = (int*)smem;  // B buffers dead now
  if ((lane & 15) == 0) {
#pragma unroll
    for (int T = 0; T < 2; ++T)
#pragma unroll
      for (int q = 0; q < 4; ++q) {
        int row = w * 32 + T * 16 + (lane >> 4) * 4 + q;
        int p = p0 + row;
        sbest[row] = i1[T][q];
        out_idx[p] = (float)i1[T][q];
        float g2 = m2[T][q] - m1[T][q];
        float g3 = m3[T][q] - m1[T][q];
        if (g3 < MARGIN) {
          int pos = atomicAdd(cnt + 1, 1);
          if (pos < capB) listB[pos] = p;
        } else if (g2 < MARGIN) {
          int pos = atomicAdd(cnt, 1);
          if (pos < capA) {
            listA[2 * pos] = p | (i1[T][q] << 16);
            listA[2 * pos + 1] = i2a[T][q] | (i3a[T][q] << 16);
          }
        }
      }
  }
  __syncthreads();

  // ---- zq gather: coalesced over px ----
  {
    const int px = t & 127;
    const int best = sbest[px];
    const int ch0g = (t >> 7) * 128;
    const float* crow = cb + (size_t)best * CDIM + ch0g;
    float* ob = out_zq + (size_t)b * (CDIM * HWSZ) + (size_t)ch0g * HWSZ + hw0 + px;
#pragma unroll 4
    for (int c2 = 0; c2 < 128; c2 += 4) {
      float4 v = *(const float4*)(crow + c2);
      ob[(size_t)(c2 + 0) * HWSZ] = v.x;
      ob[(size_t)(c2 + 1) * HWSZ] = v.y;
      ob[(size_t)(c2 + 2) * HWSZ] = v.z;
      ob[(size_t)(c2 + 3) * HWSZ] = v.w;
    }
  }
}

// Stage 2a: exact f64 check of 3 candidate codes. One wave per entry;
// lanes span channels (fully coalesced codebook reads).
__launch_bounds__(256)
__global__ void vq_resolve3(const float* __restrict__ z,
                            const float* __restrict__ cb,
                            const double* __restrict__ cbn64,
                            float* __restrict__ out_zq,
                            float* __restrict__ out_idx,
                            const int* __restrict__ cnt,
                            const int* __restrict__ listA, int capA) {
  const int lane = threadIdx.x & 63;
  const int wid = (blockIdx.x * blockDim.x + threadIdx.x) >> 6;
  const int nw = (gridDim.x * blockDim.x) >> 6;
  int n = cnt[0];
  if (n > capA) n = capA;

  for (int i = wid; i < n; i += nw) {
    const int e0 = listA[2 * i];
    const int e1 = listA[2 * i + 1];
    const int p = e0 & 0xFFFF;
    int cand[3];
    cand[0] = (e0 >> 16) & 1023;
    cand[1] = e1 & 0xFFFF;
    cand[2] = (e1 >> 16) & 1023;
    const int b = p >> 12;
    const int hw = p & (HWSZ - 1);
    const float* zb = z + (size_t)b * (CDIM * HWSZ) + hw;
    const int ch0 = lane * 4;

    double zv[4];
#pragma unroll
    for (int j = 0; j < 4; ++j) zv[j] = (double)zb[(size_t)(ch0 + j) * HWSZ];

    double d[3];
#pragma unroll
    for (int tt = 0; tt < 3; ++tt) {
      float4 cv = *(const float4*)(cb + (size_t)cand[tt] * CDIM + ch0);
      double s = zv[0] * (double)cv.x;
      s = fma(zv[1], (double)cv.y, s);
      s = fma(zv[2], (double)cv.z, s);
      s = fma(zv[3], (double)cv.w, s);
#pragma unroll
      for (int off = 32; off; off >>= 1) s += __shfl_xor(s, off, 64);
      d[tt] = fma(-2.0, s, cbn64[cand[tt]]);
    }

    double bd = d[0];
    int bi = cand[0];
#pragma unroll
    for (int tt = 1; tt < 3; ++tt) {
      bool takes = (d[tt] < bd) || (d[tt] == bd && cand[tt] < bi);
      bd = takes ? d[tt] : bd;
      bi = takes ? cand[tt] : bi;
    }

    if (lane == 0) out_idx[p] = (float)bi;
    float4 cv = *(const float4*)(cb + (size_t)bi * CDIM + ch0);
    float* ob = out_zq + (size_t)b * (CDIM * HWSZ) + hw;
    ob[(size_t)(ch0 + 0) * HWSZ] = cv.x;
    ob[(size_t)(ch0 + 1) * HWSZ] = cv.y;
    ob[(size_t)(ch0 + 2) * HWSZ] = cv.z;
    ob[(size_t)(ch0 + 3) * HWSZ] = cv.w;
  }
}

// Stage 2b: exact f64 full scan for triple-near-tie pixels. One block/pixel;
// 4-thread group per code, threads span channel quarters (coalesced).
__launch_bounds__(256)
__global__ void vq_fullscan(const float* __restrict__ z,
                            const float* __restrict__ cb,
                            const double* __restrict__ cbn64,
                            float* __restrict__ out_zq,
                            float* __restrict__ out_idx,
                            const int* __restrict__ cnt,
                            const int* __restrict__ listB, int capB) {
  __shared__ double zl[256];
  __shared__ double sd[4];
  __shared__ int si[4];
  __shared__ int sfin;
  int n = cnt[1];
  if (n > capB) n = capB;
  const int t = threadIdx.x;
  const int w = t >> 6;
  const int lane = t & 63;

  for (int i = blockIdx.x; i < n; i += gridDim.x) {
    const int p = listB[i];
    const int b = p >> 12;
    const int hw = p & (HWSZ - 1);
    const float* zb = z + (size_t)b * (CDIM * HWSZ) + hw;
    zl[t] = (double)zb[(size_t)t * HWSZ];
    __syncthreads();

    const int g = t >> 2;      // 64 code-groups
    const int sub = t & 3;     // channel quarter
    const double* zq4 = zl + sub * 64;
    double bd = 1e300;
    int bi = 0;

    for (int j = 0; j < 16; ++j) {
      const int code = g + 64 * j;
      const float* crow = cb + (size_t)code * CDIM + sub * 64;
      double s = 0.0;
#pragma unroll
      for (int q4 = 0; q4 < 64; q4 += 4) {
        float4 cv = *(const float4*)(crow + q4);
        s = fma(zq4[q4 + 0], (double)cv.x, s);
        s = fma(zq4[q4 + 1], (double)cv.y, s);
        s = fma(zq4[q4 + 2], (double)cv.z, s);
        s = fma(zq4[q4 + 3], (double)cv.w, s);
      }
      s += __shfl_xor(s, 1, 64);
      s += __shfl_xor(s, 2, 64);
      double d = fma(-2.0, s, cbn64[code]);
      bool takes = (d < bd) || (d == bd && code < bi);
      bd = takes ? d : bd;
      bi = takes ? code : bi;
    }

    // wave reduce across groups (lanes differ at bits 2..5)
#pragma unroll
    for (int off = 4; off <= 32; off <<= 1) {
      double od = __shfl_xor(bd, off, 64);
      int oi = __shfl_xor(bi, off, 64);
      bool takes = (od < bd) || (od == bd && oi < bi);
      bd = takes ? od : bd;
      bi = takes ? oi : bi;
    }
    if (lane == 0) { sd[w] = bd; si[w] = bi; }
    __syncthreads();
    if (t == 0) {
      double fd = sd[0];
      int fi = si[0];
#pragma unroll
      for (int k = 1; k < 4; ++k) {
        bool takes = (sd[k] < fd) || (sd[k] == fd && si[k] < fi);
        fd = takes ? sd[k] : fd;
        fi = takes ? si[k] : fi;
      }
      sfin = fi;
      out_idx[p] = (float)fi;
    }
    __syncthreads();
    const int best = sfin;
    float* ob = out_zq + (size_t)b * (CDIM * HWSZ) + hw;
    ob[(size_t)t * HWSZ] = cb[(size_t)best * CDIM + t];
    __syncthreads();  // zl reuse next iteration
  }
}

extern "C" void kernel_launch(void* const* d_in, const int* in_sizes, int n_in,
                              void* d_out, int out_size, void* d_ws, size_t ws_size,
                              hipStream_t stream) {
  const float* z = (const float*)d_in[0];
  const float* cb = (const float*)d_in[1];
  float* out = (float*)d_out;
  float* out_zq = out;
  float* out_idx = out + ZQ_ELEMS;

  char* ws = (char*)d_ws;
  unsigned short* cbswz = (unsigned short*)(ws + WS_CBSWZ);
  double* cbn64 = (double*)(ws + WS_CBN64);
  float* cbn32 = (float*)(ws + WS_CBN32);
  int* cnt = (int*)(ws + WS_CNT);

  long long avail = (long long)ws_size - WS_LISTS;
  if (avail < 0) avail = 0;
  long long capA_ll = (avail * 2 / 3) / 8;   // 8 B per listA entry
  if (capA_ll > NPIX) capA_ll = NPIX;
  int capA = (int)capA_ll;
  int* listA = (int*)(ws + WS_LISTS);
  int* listB = (int*)(ws + WS_LISTS + (size_t)capA * 8);
  long long capB_ll = (avail - (long long)capA * 8) / 4;
  if (capB_ll > NPIX) capB_ll = NPIX;
  if (capB_ll < 0) capB_ll = 0;
  int capB = (int)capB_ll;

  hipMemsetAsync(cnt, 0, 8, stream);
  prep_norms<<<4, 256, 0, stream>>>(cb, cbn64, cbn32);
  prep_cbswz<<<256, 256, 0, stream>>>(cb, cbswz);
  vq_stage1<<<512, 256, 65536, stream>>>(z, cb, cbswz, cbn32, out_zq, out_idx,
                                         cnt, listA, capA, listB, capB);
  vq_resolve3<<<256, 256, 0, stream>>>(z, cb, cbn64, out_zq, out_idx,
                                       cnt, listA, capA);
  vq_fullscan<<<512, 256, 0, stream>>>(z, cb, cbn64, out_zq, out_idx,
                                       cnt, listB, capB);
}